// Round 1
// baseline (95.973 us; speedup 1.0000x reference)
//
#include <hip/hip_runtime.h>

#define B_    32
#define CIN_  64
#define COUT_ 64
#define IMG_  128

// ---------------- Kernel A: xs[b][h][w] = sum_c x[b][c][h][w] ----------------
// One thread = one float4 (4 pixels). Grid covers B*IMG*IMG/4 = 131072 threads.
__global__ __launch_bounds__(256) void ch_sum_kernel(const float* __restrict__ x,
                                                     float* __restrict__ xs) {
    const int PIX4 = IMG_ * IMG_ / 4;            // 4096 float4 per plane
    int i = blockIdx.x * 256 + threadIdx.x;      // 0 .. B_*PIX4-1 (exact grid)
    int b = i / PIX4;
    int p = i - b * PIX4;
    const float4* xp = reinterpret_cast<const float4*>(x) + (size_t)b * CIN_ * PIX4 + p;
    float4 acc = make_float4(0.f, 0.f, 0.f, 0.f);
#pragma unroll 8
    for (int c = 0; c < CIN_; ++c) {
        float4 v = xp[(size_t)c * PIX4];
        acc.x += v.x; acc.y += v.y; acc.z += v.z; acc.w += v.w;
    }
    reinterpret_cast<float4*>(xs)[i] = acc;
}

// ---------------- Kernel B: out[b][co] = conv3x3(xs[b], k[co]) + CIN*bias[co] ----
// blockIdx.y = cout (kernel weights wave-uniform -> scalar loads).
// One thread = one float4 of output pixels. Zero padding at borders.
__global__ __launch_bounds__(256) void conv3x3_kernel(const float* __restrict__ xs,
                                                      const float* __restrict__ kern,
                                                      const float* __restrict__ bias,
                                                      float* __restrict__ out) {
    const int W4   = IMG_ / 4;        // 32 float4 per row
    const int PIX4 = IMG_ * W4;       // 4096 float4 per plane

    const int cout = blockIdx.y;
    const float k00 = kern[cout * 9 + 0], k01 = kern[cout * 9 + 1], k02 = kern[cout * 9 + 2];
    const float k10 = kern[cout * 9 + 3], k11 = kern[cout * 9 + 4], k12 = kern[cout * 9 + 5];
    const float k20 = kern[cout * 9 + 6], k21 = kern[cout * 9 + 7], k22 = kern[cout * 9 + 8];
    const float bv  = (float)CIN_ * bias[cout];

    int i = blockIdx.x * 256 + threadIdx.x;      // over B*IMG*W4 = 131072 (exact grid)
    int b   = i / (IMG_ * W4);
    int rem = i - b * (IMG_ * W4);
    int h   = rem / W4;
    int w4  = rem - h * W4;

    const float* base = xs + (size_t)b * IMG_ * IMG_;

    float acc0 = bv, acc1 = bv, acc2 = bv, acc3 = bv;

#pragma unroll
    for (int dr = -1; dr <= 1; ++dr) {
        const int r = h + dr;
        float kw0, kw1, kw2;
        if (dr == -1)      { kw0 = k00; kw1 = k01; kw2 = k02; }
        else if (dr == 0)  { kw0 = k10; kw1 = k11; kw2 = k12; }
        else               { kw0 = k20; kw1 = k21; kw2 = k22; }

        float v0 = 0.f, v1 = 0.f, v2 = 0.f, v3 = 0.f, vl = 0.f, vr = 0.f;
        if (r >= 0 && r < IMG_) {
            const float* rp = base + r * IMG_ + w4 * 4;
            float4 c = *reinterpret_cast<const float4*>(rp);
            v0 = c.x; v1 = c.y; v2 = c.z; v3 = c.w;
            vl = (w4 > 0)      ? rp[-1] : 0.f;
            vr = (w4 < W4 - 1) ? rp[4]  : 0.f;
        }
        acc0 += kw0 * vl + kw1 * v0 + kw2 * v1;
        acc1 += kw0 * v0 + kw1 * v1 + kw2 * v2;
        acc2 += kw0 * v1 + kw1 * v2 + kw2 * v3;
        acc3 += kw0 * v2 + kw1 * v3 + kw2 * vr;
    }

    const size_t o = (size_t)(b * COUT_ + cout) * PIX4 + (size_t)h * W4 + w4;
    reinterpret_cast<float4*>(out)[o] = make_float4(acc0, acc1, acc2, acc3);
}

extern "C" void kernel_launch(void* const* d_in, const int* in_sizes, int n_in,
                              void* d_out, int out_size, void* d_ws, size_t ws_size,
                              hipStream_t stream) {
    const float* x    = (const float*)d_in[0];   // (32,64,128,128) f32
    const float* kern = (const float*)d_in[1];   // (64,3,3) f32
    const float* bias = (const float*)d_in[2];   // (64,1,1,1) f32
    float* out = (float*)d_out;                  // (32,64,128,128) f32
    float* xs  = (float*)d_ws;                   // (32,128,128) f32 = 2 MiB scratch

    const int n4 = B_ * IMG_ * IMG_ / 4;         // 131072
    ch_sum_kernel<<<dim3(n4 / 256), 256, 0, stream>>>(x, xs);

    dim3 g2(n4 / 256, COUT_);                    // (512, 64)
    conv3x3_kernel<<<g2, 256, 0, stream>>>(xs, kern, bias, out);
}

// Round 2
// 79.037 us; speedup vs baseline: 1.2143x; 1.2143x over previous
//
#include <hip/hip_runtime.h>

#define B_    32
#define CIN_  64
#define COUT_ 64
#define IMG_  128
#define TH_   8                 // output rows per block
#define W4_   (IMG_ / 4)        // 32 float4 per row
#define PIX4_ (IMG_ * W4_)      // 4096 float4 per plane

// One block = one (b, 8-row tile). Phase 1: channel-sum the 10-row halo tile
// into LDS. Phase 2: each thread owns one (row, w4) output position, keeps its
// 3x6 stencil in registers, and loops over all 64 couts (weights are
// wave-uniform scalar loads), streaming float4 stores.
__global__ __launch_bounds__(256) void fused_gc_kernel(const float* __restrict__ x,
                                                       const float* __restrict__ kern,
                                                       const float* __restrict__ bias,
                                                       float* __restrict__ out) {
    __shared__ float xs[(TH_ + 2) * IMG_];   // 10 x 128 floats = 5 KB

    const int tile = blockIdx.x;             // 0..15
    const int b    = blockIdx.y;             // 0..31
    const int h0   = tile * TH_;             // first output row of this tile
    const int tid  = threadIdx.x;

    // ---- Phase 1: xs[r][.] = sum_c x[b][c][h0-1+r][.],  r = 0..9 ----
    const float4* xb = reinterpret_cast<const float4*>(x) + (size_t)b * CIN_ * PIX4_;
    for (int pos = tid; pos < (TH_ + 2) * W4_; pos += 256) {   // 320 float4 positions
        const int r   = pos >> 5;            // 0..9
        const int w4  = pos & 31;
        const int row = h0 - 1 + r;          // -1 .. 128
        float4 acc = make_float4(0.f, 0.f, 0.f, 0.f);
        if (row >= 0 && row < IMG_) {
            const float4* p = xb + row * W4_ + w4;
#pragma unroll 8
            for (int c = 0; c < CIN_; ++c) {
                float4 v = p[(size_t)c * PIX4_];
                acc.x += v.x; acc.y += v.y; acc.z += v.z; acc.w += v.w;
            }
        }
        reinterpret_cast<float4*>(xs)[pos] = acc;
    }
    __syncthreads();

    // ---- Phase 2: conv 3x3, all 64 couts per thread ----
    const int hh = tid >> 5;                 // 0..7  local output row
    const int w4 = tid & 31;                 // 0..31 float4 column

    float v[3][6];
#pragma unroll
    for (int r = 0; r < 3; ++r) {
        const float* rp = &xs[(hh + r) * IMG_ + w4 * 4];
        float4 c = *reinterpret_cast<const float4*>(rp);
        v[r][1] = c.x; v[r][2] = c.y; v[r][3] = c.z; v[r][4] = c.w;
        v[r][0] = (w4 > 0)  ? rp[-1] : 0.f;
        v[r][5] = (w4 < 31) ? rp[4]  : 0.f;
    }

    float4* outp = reinterpret_cast<float4*>(out)
                 + (size_t)b * COUT_ * PIX4_ + (h0 + hh) * W4_ + w4;

#pragma unroll 2
    for (int co = 0; co < COUT_; ++co) {
        const float* kw = kern + co * 9;
        const float k0 = kw[0], k1 = kw[1], k2 = kw[2];
        const float k3 = kw[3], k4 = kw[4], k5 = kw[5];
        const float k6 = kw[6], k7 = kw[7], k8 = kw[8];
        const float bv = (float)CIN_ * bias[co];

        float a[4];
#pragma unroll
        for (int j = 0; j < 4; ++j) {
            a[j] = bv
                 + k0 * v[0][j] + k1 * v[0][j + 1] + k2 * v[0][j + 2]
                 + k3 * v[1][j] + k4 * v[1][j + 1] + k5 * v[1][j + 2]
                 + k6 * v[2][j] + k7 * v[2][j + 1] + k8 * v[2][j + 2];
        }
        outp[(size_t)co * PIX4_] = make_float4(a[0], a[1], a[2], a[3]);
    }
}

extern "C" void kernel_launch(void* const* d_in, const int* in_sizes, int n_in,
                              void* d_out, int out_size, void* d_ws, size_t ws_size,
                              hipStream_t stream) {
    const float* x    = (const float*)d_in[0];   // (32,64,128,128) f32
    const float* kern = (const float*)d_in[1];   // (64,3,3) f32
    const float* bias = (const float*)d_in[2];   // (64,1,1,1) f32
    float* out = (float*)d_out;                  // (32,64,128,128) f32

    dim3 grid(IMG_ / TH_, B_);                   // (16, 32) = 512 blocks
    fused_gc_kernel<<<grid, 256, 0, stream>>>(x, kern, bias, out);
}